// Round 4
// baseline (318.519 us; speedup 1.0000x reference)
//
#include <hip/hip_runtime.h>
#include <hip/hip_bf16.h>

#define HW 4096
#define NC 512
#define NB 4

typedef float f32x4 __attribute__((ext_vector_type(4)));
typedef short bf16x8 __attribute__((ext_vector_type(8)));
typedef unsigned short ushort_t;

#define GLOAD_LDS(g, s) __builtin_amdgcn_global_load_lds((const __attribute__((address_space(1))) void*)(g), (__attribute__((address_space(3))) void*)(s), 16, 0, 0)

__device__ __forceinline__ unsigned short f2bf(float f){
  unsigned int u = __builtin_bit_cast(unsigned int, f);
  u += 0x7FFFu + ((u >> 16) & 1u);
  return (unsigned short)(u >> 16);
}
__device__ __forceinline__ float bf2f(unsigned short h){
  unsigned int u = ((unsigned int)h) << 16;
  return __builtin_bit_cast(float, u);
}

// ---------------- W -> bf16 hi (+lo for q/k rows 0..127) ----------------
__global__ __launch_bounds__(256) void wsplit_kernel(
    const float* __restrict__ Wq, const float* __restrict__ Wk,
    const float* __restrict__ Wv, ushort_t* __restrict__ wh, ushort_t* __restrict__ wl)
{
  long e = ((long)blockIdx.x * 256 + threadIdx.x) * 8;
  int r = (int)(e >> 9), c = (int)(e & 511);
  const float* src = (r < 64)  ? Wq + (long)r * 512 + c
                   : (r < 128) ? Wk + (long)(r - 64) * 512 + c
                               : Wv + (long)(r - 128) * 512 + c;
  f32x4 v0 = *reinterpret_cast<const f32x4*>(src);
  f32x4 v1 = *reinterpret_cast<const f32x4*>(src + 4);
  ushort_t h[8], l[8];
  #pragma unroll
  for (int j = 0; j < 4; j++){ h[j] = f2bf(v0[j]); l[j] = f2bf(v0[j] - bf2f(h[j])); }
  #pragma unroll
  for (int j = 0; j < 4; j++){ h[4+j] = f2bf(v1[j]); l[4+j] = f2bf(v1[j] - bf2f(h[4+j])); }
  *reinterpret_cast<bf16x8*>(wh + e) = *reinterpret_cast<bf16x8*>(h);
  if (r < 128) *reinterpret_cast<bf16x8*>(wl + e) = *reinterpret_cast<bf16x8*>(l);
}

// ---------------- x [b][c][px] fp32 -> xt hi/lo [b][px][c] bf16 ----------------
__global__ __launch_bounds__(256) void split_kernel(
    const float* __restrict__ x, ushort_t* __restrict__ xth, ushort_t* __restrict__ xtl)
{
  const int i0 = blockIdx.x * 64;
  const int c0 = blockIdx.y * 64;
  const int b  = blockIdx.z;
  const int tid = threadIdx.x;
  const int tx = tid & 63, ty = tid >> 6;
  __shared__ float ts[64][65];
  #pragma unroll
  for (int u = 0; u < 16; u++){
    int cl = ty * 16 + u;
    ts[cl][tx] = x[((long)b * NC + c0 + cl) * HW + i0 + tx];
  }
  __syncthreads();
  const int px = tid >> 2;
  const int cs = (tid & 3) * 16;
  ushort_t h[16], l[16];
  #pragma unroll
  for (int e = 0; e < 16; e++){
    float v = ts[cs + e][px];
    h[e] = f2bf(v);
    l[e] = f2bf(v - bf2f(h[e]));
  }
  long base = ((long)b * HW + i0 + px) * 512 + c0 + cs;
  *reinterpret_cast<bf16x8*>(xth + base)     = *reinterpret_cast<bf16x8*>(h);
  *reinterpret_cast<bf16x8*>(xth + base + 8) = *reinterpret_cast<bf16x8*>(h + 8);
  *reinterpret_cast<bf16x8*>(xtl + base)     = *reinterpret_cast<bf16x8*>(l);
  *reinterpret_cast<bf16x8*>(xtl + base + 8) = *reinterpret_cast<bf16x8*>(l + 8);
}

// ---------------- MFMA projection GEMM (unchanged from round 3) ----------------
__global__ __launch_bounds__(256) void gemm_kernel(
    const ushort_t* __restrict__ xth, const ushort_t* __restrict__ xtl,
    const ushort_t* __restrict__ wh, const ushort_t* __restrict__ wl,
    const float* __restrict__ bq, const float* __restrict__ bk, const float* __restrict__ bv,
    ushort_t* __restrict__ qhi, ushort_t* __restrict__ qlo,
    ushort_t* __restrict__ khi, ushort_t* __restrict__ klo,
    ushort_t* __restrict__ vv)
{
  extern __shared__ char lds[];
  const int it = blockIdx.x;
  const int rg = blockIdx.y;
  const int b  = blockIdx.z;
  const int i0 = it * 128;
  const int tid = threadIdx.x;
  const int w = tid >> 6;
  const int lane = tid & 63;
  const int g = lane >> 4, n = lane & 15;
  const int wy = w >> 1, wx = w & 1;

  f32x4 acc[4][4];
  #pragma unroll
  for (int a = 0; a < 4; a++)
    #pragma unroll
    for (int m = 0; m < 4; m++) acc[a][m] = (f32x4){0.f, 0.f, 0.f, 0.f};

  const long xrow = (long)b * HW + i0;

  auto stage = [&](int bsel, int c0s){
    char* dbase = lds + bsel * 32768 + (w << 10);
    #pragma unroll
    for (int u = 0; u < 4; u++){
      int idx = (u << 8) | tid;
      int px = idx >> 3;
      int chs = (idx & 7) ^ (px & 7);
      long go = (xrow + px) * 512 + c0s + chs * 8;
      GLOAD_LDS(xth + go, dbase + (u << 12));
      GLOAD_LDS(xtl + go, dbase + 16384 + (u << 12));
    }
  };

  stage(0, 0);
  asm volatile("s_waitcnt vmcnt(0)" ::: "memory");
  __syncthreads();

  int cur = 0;
  for (int t = 0; t < 8; t++){
    const int c0 = t << 6;
    bf16x8 wfh[4][2], wfl[4][2];
    #pragma unroll
    for (int a = 0; a < 4; a++){
      long R = (long)(rg * 128 + wx * 64 + a * 16 + n) * 512 + c0 + g * 8;
      wfh[a][0] = *reinterpret_cast<const bf16x8*>(wh + R);
      wfh[a][1] = *reinterpret_cast<const bf16x8*>(wh + R + 32);
    }
    if (rg == 0){
      #pragma unroll
      for (int a = 0; a < 4; a++){
        long R = (long)(wx * 64 + a * 16 + n) * 512 + c0 + g * 8;
        wfl[a][0] = *reinterpret_cast<const bf16x8*>(wl + R);
        wfl[a][1] = *reinterpret_cast<const bf16x8*>(wl + R + 32);
      }
    }
    if (t < 7) stage(cur ^ 1, (t + 1) << 6);
    bf16x8 xh[4][2], xl[4][2];
    const char* buf = lds + cur * 32768;
    #pragma unroll
    for (int m = 0; m < 4; m++){
      int px = wy * 64 + m * 16 + n;
      const char* row = buf + px * 128;
      #pragma unroll
      for (int ks = 0; ks < 2; ks++){
        int off = (((ks << 2) | g) ^ (px & 7)) << 4;
        xh[m][ks] = *reinterpret_cast<const bf16x8*>(row + off);
        xl[m][ks] = *reinterpret_cast<const bf16x8*>(row + 16384 + off);
      }
    }
    __builtin_amdgcn_s_setprio(1);
    if (rg == 0){
      #pragma unroll
      for (int a = 0; a < 4; a++)
        #pragma unroll
        for (int m = 0; m < 4; m++)
          #pragma unroll
          for (int ks = 0; ks < 2; ks++){
            acc[a][m] = __builtin_amdgcn_mfma_f32_16x16x32_bf16(xh[m][ks], wfh[a][ks], acc[a][m], 0, 0, 0);
            acc[a][m] = __builtin_amdgcn_mfma_f32_16x16x32_bf16(xl[m][ks], wfh[a][ks], acc[a][m], 0, 0, 0);
            acc[a][m] = __builtin_amdgcn_mfma_f32_16x16x32_bf16(xh[m][ks], wfl[a][ks], acc[a][m], 0, 0, 0);
          }
    } else {
      #pragma unroll
      for (int a = 0; a < 4; a++)
        #pragma unroll
        for (int m = 0; m < 4; m++)
          #pragma unroll
          for (int ks = 0; ks < 2; ks++){
            acc[a][m] = __builtin_amdgcn_mfma_f32_16x16x32_bf16(wfh[a][ks], xh[m][ks], acc[a][m], 0, 0, 0);
            acc[a][m] = __builtin_amdgcn_mfma_f32_16x16x32_bf16(wfh[a][ks], xl[m][ks], acc[a][m], 0, 0, 0);
          }
    }
    __builtin_amdgcn_s_setprio(0);
    asm volatile("s_waitcnt vmcnt(0)" ::: "memory");
    __syncthreads();
    cur ^= 1;
  }

  if (rg == 0){
    ushort_t* hs = wx ? khi : qhi;
    ushort_t* ls = wx ? klo : qlo;
    const float* bias = wx ? bk : bq;
    #pragma unroll
    for (int a = 0; a < 4; a++){
      float bb = bias[a * 16 + n];
      #pragma unroll
      for (int m = 0; m < 4; m++){
        #pragma unroll
        for (int r4 = 0; r4 < 4; r4++){
          int px = wy * 64 + m * 16 + g * 4 + r4;
          float v = acc[a][m][r4] + bb;
          ushort_t h = f2bf(v);
          ushort_t l = f2bf(v - bf2f(h));
          long ad = (xrow + px) * 64 + a * 16 + n;
          hs[ad] = h;
          ls[ad] = l;
        }
      }
    }
  } else {
    #pragma unroll
    for (int a = 0; a < 4; a++){
      #pragma unroll
      for (int r4 = 0; r4 < 4; r4++){
        int C = (rg - 1) * 128 + wx * 64 + a * 16 + g * 4 + r4;
        float bb = bv[C];
        #pragma unroll
        for (int m = 0; m < 4; m++){
          int px = wy * 64 + m * 16 + n;
          vv[((long)b * NC + C) * HW + i0 + px] = f2bf(acc[a][m][r4] + bb);
        }
      }
    }
  }
}

// ---------------- flash attention, j-split x2, 128 q rows/block ----------------
// grid (32 qtiles, 2 j-halves, NB), block 512 (8 waves).
// wave w: rg = w>>1 -> q rows [qt*128+rg*32, +32) (2 m-subtiles), ch = w&1 -> 256-ch half.
// 64 iterations over 32-j subtiles of this block's 2048-j half.
// LDS: [0,16K) K dbuf (8KB each: hi 4K + lo 4K, [32j][64d] chunk-swizzled)
//      [16K,80K) V dbuf (32KB each: [512c][32j] chunk-swizzled)
//      [80K, +36K) per-wave P scratch (32 rows x 144B, 16B-chunk XOR swizzle)
__global__ __launch_bounds__(512, 2) void attn_kernel(
    const ushort_t* __restrict__ qhi, const ushort_t* __restrict__ qlo,
    const ushort_t* __restrict__ khi, const ushort_t* __restrict__ klo,
    const ushort_t* __restrict__ vv,
    ushort_t* __restrict__ p0, ushort_t* __restrict__ p1,
    float* __restrict__ mbuf, float* __restrict__ lbuf)
{
  extern __shared__ char smem[];
  const int qt = blockIdx.x;
  const int jh = blockIdx.y;
  const int b  = blockIdx.z;
  const int tid = threadIdx.x;
  const int w = tid >> 6;
  const int lane = tid & 63;
  const int g = lane >> 4, n = lane & 15;
  const int rg = w >> 1, ch = w & 1;
  const int i0w = qt * 128 + rg * 32;
  const int c0w = ch * 256;
  const int jbase = jh * 2048;

  char* pswb = smem + 81920 + w * 4608;

  // K staging geometry: 512 chunks (hi 256 + lo 256), 1 per thread
  const int ksurf = w >> 2;                    // 0 = hi, 1 = lo
  const int ks_s  = ((w & 3) << 6) | lane;     // chunk within 4KB surface
  const int ks_j  = ks_s >> 3;
  const int ks_d  = (ks_s & 7) ^ (ks_j & 7);
  const ushort_t* ksrc = ksurf ? klo : khi;
  const long kgrow = ((long)b * HW + ks_j) * 64 + ks_d * 8;

  auto stageK = [&](int bsel, int j0){
    char* dst = smem + bsel * 8192 + ksurf * 4096 + ((w & 3) << 10);
    GLOAD_LDS(ksrc + kgrow + (long)j0 * 64, dst);
  };
  auto stageV = [&](int bsel, int j0){
    char* dbase = smem + 16384 + bsel * 32768 + (w << 10);
    #pragma unroll
    for (int u = 0; u < 4; u++){
      int s = (u << 9) | tid;
      int c = s >> 2, q = s & 3;
      int jb = q ^ (c & 3) ^ ((c >> 2) & 3);
      GLOAD_LDS(vv + ((long)b * NC + c) * HW + j0 + jb * 8, dbase + (u << 13));
    }
  };

  // Q fragments: 2 m-subtiles x hi/lo x 2 ks
  bf16x8 aqh[2][2], aql[2][2];
  #pragma unroll
  for (int m = 0; m < 2; m++){
    long qb = ((long)b * HW + i0w + m * 16 + n) * 64 + g * 8;
    aqh[m][0] = *reinterpret_cast<const bf16x8*>(qhi + qb);
    aqh[m][1] = *reinterpret_cast<const bf16x8*>(qhi + qb + 32);
    aql[m][0] = *reinterpret_cast<const bf16x8*>(qlo + qb);
    aql[m][1] = *reinterpret_cast<const bf16x8*>(qlo + qb + 32);
  }

  f32x4 acc[2][16];
  #pragma unroll
  for (int m = 0; m < 2; m++)
    #pragma unroll
    for (int t = 0; t < 16; t++) acc[m][t] = (f32x4){0.f, 0.f, 0.f, 0.f};
  float mrow[2][4], lrow[2][4];
  #pragma unroll
  for (int m = 0; m < 2; m++)
    #pragma unroll
    for (int r = 0; r < 4; r++){ mrow[m][r] = -1e30f; lrow[m][r] = 0.f; }

  stageK(0, jbase);
  stageV(0, jbase);
  asm volatile("s_waitcnt vmcnt(0)" ::: "memory");
  __syncthreads();

  int cur = 0;
  for (int t = 0; t < 64; t++){
    // prefetch next subtile (stays in flight across compute)
    if (t < 63){
      stageK(cur ^ 1, jbase + (t + 1) * 32);
      stageV(cur ^ 1, jbase + (t + 1) * 32);
    }
    // ---- QK (3-term hi/lo): S[q, j] for 32 q x 32 j
    f32x4 sv[2][2];
    {
      const char* kb0 = smem + cur * 8192;
      __builtin_amdgcn_s_setprio(1);
      #pragma unroll
      for (int nt = 0; nt < 2; nt++){
        int jl = nt * 16 + n;
        const char* kb = kb0 + jl * 128;
        int x0 = (g ^ (jl & 7)) << 4;
        int x1 = ((4 + g) ^ (jl & 7)) << 4;
        bf16x8 bh0 = *(const bf16x8*)(kb + x0);
        bf16x8 bh1 = *(const bf16x8*)(kb + x1);
        bf16x8 bl0 = *(const bf16x8*)(kb + 4096 + x0);
        bf16x8 bl1 = *(const bf16x8*)(kb + 4096 + x1);
        #pragma unroll
        for (int m = 0; m < 2; m++){
          f32x4 s = (f32x4){0.f, 0.f, 0.f, 0.f};
          s = __builtin_amdgcn_mfma_f32_16x16x32_bf16(aqh[m][0], bh0, s, 0, 0, 0);
          s = __builtin_amdgcn_mfma_f32_16x16x32_bf16(aqh[m][1], bh1, s, 0, 0, 0);
          s = __builtin_amdgcn_mfma_f32_16x16x32_bf16(aql[m][0], bh0, s, 0, 0, 0);
          s = __builtin_amdgcn_mfma_f32_16x16x32_bf16(aql[m][1], bh1, s, 0, 0, 0);
          s = __builtin_amdgcn_mfma_f32_16x16x32_bf16(aqh[m][0], bl0, s, 0, 0, 0);
          s = __builtin_amdgcn_mfma_f32_16x16x32_bf16(aqh[m][1], bl1, s, 0, 0, 0);
          sv[m][nt] = s;
        }
      }
      __builtin_amdgcn_s_setprio(0);
    }
    // ---- online softmax (rows q = m*16 + g*4 + r, cols j across 16 n-lanes)
    #pragma unroll
    for (int m = 0; m < 2; m++){
      float mnew[4]; int upd = 0;
      #pragma unroll
      for (int r = 0; r < 4; r++){
        float tmx = fmaxf(sv[m][0][r], sv[m][1][r]);
        tmx = fmaxf(tmx, __shfl_xor(tmx, 1));
        tmx = fmaxf(tmx, __shfl_xor(tmx, 2));
        tmx = fmaxf(tmx, __shfl_xor(tmx, 4));
        tmx = fmaxf(tmx, __shfl_xor(tmx, 8));
        mnew[r] = fmaxf(mrow[m][r], tmx);
        upd |= (mnew[r] > mrow[m][r]) ? 1 : 0;
      }
      if (__any(upd)){
        #pragma unroll
        for (int r = 0; r < 4; r++){
          float sc = __expf(mrow[m][r] - mnew[r]);
          lrow[m][r] *= sc;
          mrow[m][r] = mnew[r];
          #pragma unroll
          for (int ct = 0; ct < 16; ct++) acc[m][ct][r] *= sc;
        }
      }
      float p[2][4];
      #pragma unroll
      for (int nt = 0; nt < 2; nt++)
        #pragma unroll
        for (int r = 0; r < 4; r++)
          p[nt][r] = __expf(sv[m][nt][r] - mrow[m][r]);
      #pragma unroll
      for (int r = 0; r < 4; r++){
        float rs = p[0][r] + p[1][r];
        rs += __shfl_xor(rs, 1);
        rs += __shfl_xor(rs, 2);
        rs += __shfl_xor(rs, 4);
        rs += __shfl_xor(rs, 8);
        lrow[m][r] += rs;
      }
      // P -> per-wave LDS scratch (16B-chunk XOR swizzle, row stride 144B)
      #pragma unroll
      for (int nt = 0; nt < 2; nt++)
        #pragma unroll
        for (int r = 0; r < 4; r++){
          int row = m * 16 + g * 4 + r;
          int col = nt * 16 + n;
          int sw = ((col >> 2) ^ (row & 7)) & 7;
          *(float*)(pswb + row * 144 + sw * 16 + (col & 3) * 4) = p[nt][r];
        }
    }
    // ---- reload P as A-fragments, cvt bf16
    bf16x8 pa[2];
    #pragma unroll
    for (int m = 0; m < 2; m++){
      int row = m * 16 + n;
      int s0 = ((2 * g) ^ (row & 7)) & 7;
      int s1 = ((2 * g + 1) ^ (row & 7)) & 7;
      f32x4 fa = *(const f32x4*)(pswb + row * 144 + s0 * 16);
      f32x4 fb = *(const f32x4*)(pswb + row * 144 + s1 * 16);
      bf16x8 tt;
      tt[0] = (short)f2bf(fa[0]); tt[1] = (short)f2bf(fa[1]);
      tt[2] = (short)f2bf(fa[2]); tt[3] = (short)f2bf(fa[3]);
      tt[4] = (short)f2bf(fb[0]); tt[5] = (short)f2bf(fb[1]);
      tt[6] = (short)f2bf(fb[2]); tt[7] = (short)f2bf(fb[3]);
      pa[m] = tt;
    }
    // ---- PV from V LDS tile (K = 32 j in one MFMA per ct)
    {
      const char* vb0 = smem + 16384 + cur * 32768;
      __builtin_amdgcn_s_setprio(1);
      #pragma unroll
      for (int ct = 0; ct < 16; ct++){
        int c = c0w + ct * 16 + n;
        int vp = (g ^ (c & 3) ^ ((c >> 2) & 3)) & 3;
        bf16x8 bv0 = *(const bf16x8*)(vb0 + c * 64 + vp * 16);
        #pragma unroll
        for (int m = 0; m < 2; m++)
          acc[m][ct] = __builtin_amdgcn_mfma_f32_16x16x32_bf16(pa[m], bv0, acc[m][ct], 0, 0, 0);
      }
      __builtin_amdgcn_s_setprio(0);
    }
    asm volatile("s_waitcnt vmcnt(0)" ::: "memory");
    __syncthreads();
    cur ^= 1;
  }

  // ---- epilogue: unnormalized partial bf16 [b][i][c] + per-row m,l
  ushort_t* pd = jh ? p1 : p0;
  #pragma unroll
  for (int m = 0; m < 2; m++){
    #pragma unroll
    for (int ct = 0; ct < 16; ct++){
      #pragma unroll
      for (int r = 0; r < 4; r++){
        int i = i0w + m * 16 + g * 4 + r;
        int c = c0w + ct * 16 + n;
        pd[((long)b * HW + i) * NC + c] = f2bf(acc[m][ct][r]);
      }
    }
  }
  if (ch == 0 && n == 0){
    #pragma unroll
    for (int m = 0; m < 2; m++)
      #pragma unroll
      for (int r = 0; r < 4; r++){
        int gi = b * HW + i0w + m * 16 + g * 4 + r;
        mbuf[jh * (NB * HW) + gi] = mrow[m][r];
        lbuf[jh * (NB * HW) + gi] = lrow[m][r];
      }
  }
}

// ---------------- combine halves + epilogue: out = gamma * O + x ----------------
__global__ __launch_bounds__(256) void comb_kernel(
    const ushort_t* __restrict__ p0, const ushort_t* __restrict__ p1,
    const float* __restrict__ mbuf, const float* __restrict__ lbuf,
    const float* __restrict__ x, const float* __restrict__ gamma,
    float* __restrict__ out)
{
  const int it = blockIdx.x;
  const int ct = blockIdx.y;
  const int b  = blockIdx.z;
  const int i0 = it * 64, c0 = ct * 64;
  const int tid = threadIdx.x;
  const int tx = tid & 63, ty = tid >> 6;
  __shared__ float ts[64][65];
  __shared__ float f0s[64], f1s[64];
  const float gm = gamma[0];
  if (tid < 64){
    int gi = b * HW + i0 + tid;
    float m0 = mbuf[gi], m1 = mbuf[NB * HW + gi];
    float l0 = lbuf[gi], l1 = lbuf[NB * HW + gi];
    float M = fmaxf(m0, m1);
    float w0 = __expf(m0 - M), w1 = __expf(m1 - M);
    float rden = 1.f / (w0 * l0 + w1 * l1);
    f0s[tid] = w0 * rden;
    f1s[tid] = w1 * rden;
  }
  __syncthreads();
  #pragma unroll
  for (int u = 0; u < 16; u++){
    int il = ty * 16 + u;
    long pidx = ((long)b * HW + i0 + il) * NC + c0 + tx;
    ts[il][tx] = f0s[il] * bf2f(p0[pidx]) + f1s[il] * bf2f(p1[pidx]);
  }
  __syncthreads();
  #pragma unroll
  for (int u = 0; u < 16; u++){
    int cl = ty * 16 + u;
    long idx = ((long)b * NC + c0 + cl) * HW + i0 + tx;
    out[idx] = fmaf(gm, ts[tx][cl], x[idx]);
  }
}

extern "C" void kernel_launch(void* const* d_in, const int* in_sizes, int n_in,
                              void* d_out, int out_size, void* d_ws, size_t ws_size,
                              hipStream_t stream)
{
  const float* x  = (const float*)d_in[0];
  const float* Wq = (const float*)d_in[1];
  const float* bq = (const float*)d_in[2];
  const float* Wk = (const float*)d_in[3];
  const float* bk = (const float*)d_in[4];
  const float* Wv = (const float*)d_in[5];
  const float* bv = (const float*)d_in[6];
  const float* gamma = (const float*)d_in[7];
  float* out = (float*)d_out;

  char* ws = (char*)d_ws;
  const size_t MB = 1024 * 1024;
  ushort_t* xth = (ushort_t*)(ws);                 // 16 MB, reused as partial0
  ushort_t* xtl = (ushort_t*)(ws + 16 * MB);       // 16 MB, reused as partial1
  ushort_t* wh  = (ushort_t*)(ws + 32 * MB);       // 640 KB
  ushort_t* wl  = (ushort_t*)(ws + 32 * MB + 655360);  // 128 KB
  ushort_t* qhi = (ushort_t*)(ws + 33 * MB);       // 2 MB each
  ushort_t* qlo = (ushort_t*)(ws + 35 * MB);
  ushort_t* khi = (ushort_t*)(ws + 37 * MB);
  ushort_t* klo = (ushort_t*)(ws + 39 * MB);
  ushort_t* vv  = (ushort_t*)(ws + 41 * MB);       // 16 MB
  float*    mbuf = (float*)(ws + 57 * MB);         // 128 KB
  float*    lbuf = (float*)(ws + 57 * MB + 131072);// 128 KB
  ushort_t* part0 = xth;   // alias: xt dead after gemm
  ushort_t* part1 = xtl;

  wsplit_kernel<<<dim3(160), dim3(256), 0, stream>>>(Wq, Wk, Wv, wh, wl);
  split_kernel<<<dim3(64, 8, NB), dim3(256), 0, stream>>>(x, xth, xtl);

  const int GSMEM = 65536;
  hipFuncSetAttribute((const void*)gemm_kernel,
                      hipFuncAttributeMaxDynamicSharedMemorySize, GSMEM);
  gemm_kernel<<<dim3(32, 5, NB), dim3(256), GSMEM, stream>>>(
      xth, xtl, wh, wl, bq, bk, bv, qhi, qlo, khi, klo, vv);

  const int ASMEM = 118784;  // 16K K dbuf + 64K V dbuf + 36K P scratch
  hipFuncSetAttribute((const void*)attn_kernel,
                      hipFuncAttributeMaxDynamicSharedMemorySize, ASMEM);
  attn_kernel<<<dim3(32, 2, NB), dim3(512), ASMEM, stream>>>(
      qhi, qlo, khi, klo, vv, part0, part1, mbuf, lbuf);

  comb_kernel<<<dim3(64, 8, NB), dim3(256), 0, stream>>>(
      part0, part1, mbuf, lbuf, x, gamma, out);
}